// Round 7
// baseline (734.000 us; speedup 1.0000x reference)
//
#include <hip/hip_runtime.h>

#define L  50000     // learners (GEMM M)
#define S  2000      // scenes   (GEMM K)
#define SP 2048      // K padded (table zero-filled past S)
#define D  128       // embed    (GEMM N)
#define HID 16
#define KSTEPS 63    // ceil(2000/32) k-steps of 32

typedef _Float16 f16;
typedef _Float16 half8  __attribute__((ext_vector_type(8)));
typedef float    floatx4 __attribute__((ext_vector_type(4)));

// Kernel 1: Bt[d][j] = mlp_out[j][d] in f16, d-major [128][2048], j>=2000 -> 0.
// b2 folded in: mask @ Bt^T = mask @ (h W2) + count*b2 directly.
__global__ __launch_bounds__(256) void table_kernel(
    const float* __restrict__ W1, const float* __restrict__ b1,
    const float* __restrict__ W2, const float* __restrict__ b2,
    f16* __restrict__ Bt)
{
    int t = blockIdx.x * 256 + threadIdx.x;    // [0, 128*2048)
    int d = t >> 11;
    int j = t & 2047;
    float acc = b2[d];
    float x = (float)j;
#pragma unroll
    for (int k = 0; k < HID; ++k) {
        float h = fmaxf(fmaf(x, W1[k], b1[k]), 0.0f);
        acc = fmaf(h, W2[k * D + d], acc);
    }
    Bt[t] = (j < S) ? (f16)acc : (f16)0.0f;
}

// Kernel 2: LDS-free, barrier-free mask-GEMM. Each wave owns 16 rows x 128
// cols. A fragment loaded straight from M in MFMA A-layout (lane = row
// lane&15, k-slice (lane>>4)*8), converted to f16 0/1 in registers; B
// fragments are b128 loads from the L1/L2-resident Bt. Counts from the
// same compares via xor-shfl. No __syncthreads anywhere -> waves pipeline
// independently; 1-step A double-buffer keeps 2 HBM loads in flight/wave.
__global__ __launch_bounds__(256) void gemm_mask_kernel(
    const float* __restrict__ M, const f16* __restrict__ Bt,
    float* __restrict__ out)
{
    const int  wave = threadIdx.x >> 6;
    const int  lane = threadIdx.x & 63;
    const int  m    = lane & 15;                 // A row within wave tile
    const int  kg   = lane >> 4;                 // k-slice group (0..3)
    const long r0w  = (long)blockIdx.x * 64 + wave * 16;
    const long rg   = r0w + m;
    const bool rowok = (rg < L);
    const float* __restrict__ Arow = M + (rowok ? rg : (long)(L - 1)) * S;

    floatx4 acc[8];
#pragma unroll
    for (int n = 0; n < 8; ++n) acc[n] = (floatx4){0.f, 0.f, 0.f, 0.f};
    int cnt = 0;

    // A double-buffer: 8 floats/lane = 2 float4 (32B, rows 16B-aligned: 8000%16==0)
    float4 a0 = make_float4(0.f,0.f,0.f,0.f), a1 = a0;
    if (rowok) {                                 // k = kg*8 < 32 always valid
        a0 = *(const float4*)(Arow + kg * 8);
        a1 = *(const float4*)(Arow + kg * 8 + 4);
    }

    const f16* __restrict__ Bp = Bt + m * SP;    // row (nt*16 + m), col k

    for (int ks = 0; ks < KSTEPS; ++ks) {
        // prefetch next step's A
        float4 n0 = make_float4(0.f,0.f,0.f,0.f), n1 = n0;
        {
            int kn = (ks + 1) * 32 + kg * 8;
            if (rowok && kn < S) {               // k mult of 8 -> kn+7 <= 1999
                n0 = *(const float4*)(Arow + kn);
                n1 = *(const float4*)(Arow + kn + 4);
            }
        }

        // build f16 0/1 mask fragment + count
        union { half8 h; unsigned u[4]; } af;
        unsigned b0 = (a0.x != 0.f), b1_ = (a0.y != 0.f), b2_ = (a0.z != 0.f), b3 = (a0.w != 0.f);
        unsigned b4 = (a1.x != 0.f), b5 = (a1.y != 0.f), b6 = (a1.z != 0.f), b7 = (a1.w != 0.f);
        af.u[0] = (b0 * 0x3C00u) | (b1_ * 0x3C000000u);
        af.u[1] = (b2_ * 0x3C00u) | (b3 * 0x3C000000u);
        af.u[2] = (b4 * 0x3C00u) | (b5 * 0x3C000000u);
        af.u[3] = (b6 * 0x3C00u) | (b7 * 0x3C000000u);
        cnt += (int)(b0 + b1_ + b2_ + b3 + b4 + b5 + b6 + b7);

        const f16* bp = Bp + ks * 32 + kg * 8;   // 16B-aligned
#pragma unroll
        for (int nt = 0; nt < 8; ++nt) {
            half8 bf = *(const half8*)(bp + nt * 16 * SP);
            acc[nt] = __builtin_amdgcn_mfma_f32_16x16x32_f16(af.h, bf, acc[nt], 0, 0, 0);
        }

        a0 = n0; a1 = n1;
    }

    // count for row m is spread over lanes {m, m+16, m+32, m+48}
    cnt += __shfl_xor(cnt, 16);
    cnt += __shfl_xor(cnt, 32);
    float cf = (float)cnt;

    // C/D layout (m89): col = lane&15, row = (lane>>4)*4 + reg
    float inv[4];
#pragma unroll
    for (int r = 0; r < 4; ++r) {
        float c = __shfl(cf, (lane >> 4) * 4 + r);   // that lane holds row's count
        inv[r] = 1.0f / fmaxf(c, 1.0f);
    }
#pragma unroll
    for (int nt = 0; nt < 8; ++nt) {
#pragma unroll
        for (int r = 0; r < 4; ++r) {
            long row = r0w + (lane >> 4) * 4 + r;
            if (row < L)
                out[row * D + nt * 16 + m] = acc[nt][r] * inv[r];
        }
    }
}

extern "C" void kernel_launch(void* const* d_in, const int* in_sizes, int n_in,
                              void* d_out, int out_size, void* d_ws, size_t ws_size,
                              hipStream_t stream) {
    const float* M  = (const float*)d_in[0];   // [50000, 2000]
    const float* W1 = (const float*)d_in[1];   // [1, 16]
    const float* b1 = (const float*)d_in[2];   // [16]
    const float* W2 = (const float*)d_in[3];   // [16, 128]
    const float* b2 = (const float*)d_in[4];   // [128]
    float* out = (float*)d_out;                // [50000, 128]

    f16* Bt = (f16*)d_ws;                      // 128*2048*2 = 512 KB scratch

    table_kernel<<<(D * SP) / 256, 256, 0, stream>>>(W1, b1, W2, b2, Bt);
    gemm_mask_kernel<<<(L + 63) / 64, 256, 0, stream>>>(M, Bt, out);
}

// Round 9
// 522.806 us; speedup vs baseline: 1.4040x; 1.4040x over previous
//
#include <hip/hip_runtime.h>

#define NUM_LEARNERS 50000
#define NUM_SCENES   2000
#define EMBED_DIM    128
#define HID          16

// One wave per learner row. No LDS, no compaction, no table.
//
// Algebra: h(j)[k] = relu(W1[k]*j + b1[k]) is piecewise-linear in j with one
// breakpoint. For cutoff c_k (wave-uniform), Sum_{j in nz} h[k] =
// W1[k]*S + b1[k]*C over a one-sided index range, where S = sum of nz column
// indices in range, C = count. Both come EXACTLY (integer) from the row's
// nz bitmap: 32 x 64-bit ballots captured during the coalesced scan.
// Pipeline: scan (32 ballots) -> per-granule popcount + weighted popcount
// (lane-parallel, 6-pattern trick) -> suffix scan -> 16 lane-parallel range
// lookups -> broadcast -> 16x128 matvec epilogue.
__device__ __forceinline__ int wpc32(unsigned x) {
    // sum of set-bit positions within a 32-bit word
    return __popc(x & 0xAAAAAAAAu)        + (__popc(x & 0xCCCCCCCCu) << 1)
         + (__popc(x & 0xF0F0F0F0u) << 2) + (__popc(x & 0xFF00FF00u) << 3)
         + (__popc(x & 0xFFFF0000u) << 4);
}

__global__ __launch_bounds__(256) void bitmap_mean_kernel(
    const float* __restrict__ M,
    const float* __restrict__ W1, const float* __restrict__ b1,
    const float* __restrict__ W2, const float* __restrict__ b2,
    float* __restrict__ out)
{
    const int  wave = threadIdx.x >> 6;
    const int  lane = threadIdx.x & 63;
    const long row  = (long)blockIdx.x * 4 + wave;
    const float* __restrict__ Mrow = M + row * NUM_SCENES;

    // ---- Phase 0: prefetch entire row, granule G = columns [64G, 64G+64) ----
    float v[32];
#pragma unroll
    for (int G = 0; G < 32; ++G) {
        int j = (G << 6) + lane;
        v[G] = (j < NUM_SCENES) ? Mrow[j] : 0.0f;   // only G=31 partially OOB
    }

    // ---- Phase 1: ballots -> per-lane granule bitmap (lane G holds mask_G).
    // Ballot result is wave-uniform (SGPR pair); predicated select replaces
    // the unavailable writelane builtin (v_cmp + 2 cndmask per granule).
    int vml = 0, vmh = 0;
#pragma unroll
    for (int G = 0; G < 32; ++G) {
        unsigned long long bm = __ballot(v[G] != 0.0f);
        if (lane == G) {
            vml = (int)(unsigned)bm;
            vmh = (int)(unsigned)(bm >> 32);
        }
    }

    // Per-granule count and index-sum (lanes 0..31; others are zero).
    unsigned ml = (unsigned)vml, mh = (unsigned)vmh;
    int pc = __popc(ml) + __popc(mh);
    int Sg = wpc32(ml) + wpc32(mh) + (__popc(mh) << 5) + ((lane & 31) << 6) * pc;
    if (lane >= 32) { pc = 0; Sg = 0; }

    // Inclusive suffix scan over lanes: sp[l] = sum_{G>=l} pc_G, ss likewise.
    int sp = pc, ss = Sg;
#pragma unroll
    for (int s = 1; s < 64; s <<= 1) {
        int idx = lane + s; idx = idx > 63 ? 63 : idx;   // lane63 holds 0
        sp += __shfl(sp, idx);
        ss += __shfl(ss, idx);
    }
    const int Ctot = __shfl(sp, 0);
    const int Stot = __shfl(ss, 0);

    // ---- Phase 2: 16 lane-parallel range lookups (lane k handles dim k) ----
    int kk = lane & 15;
    float w = W1[kk], b = b1[kk];
    // cutoff c: for w>0 active set is {j >= c}; w<0 active is complement.
    // Boundary elements have h==0 and contribute w*j+b==0 either way.
    float t = -b / (w != 0.0f ? w : 1.0f);
    t = fminf(fmaxf(t, -1.0f), 2001.0f);
    int c;
    if (w > 0.0f)      c = (int)floorf(t) + 1;
    else if (w < 0.0f) c = (int)ceilf(t);
    else               c = (b > 0.0f) ? 0 : NUM_SCENES;  // const dim
    c = c < 0 ? 0 : (c > NUM_SCENES ? NUM_SCENES : c);

    int gb = c >> 6, l0 = c & 63;                        // gb <= 31
    unsigned bl = (unsigned)__shfl(vml, gb);
    unsigned bh = (unsigned)__shfl(vmh, gb);
    int nidx = gb + 1;                                   // <= 32, sp[32]=0
    int CSn = __shfl(sp, nidx);
    int SSn = __shfl(ss, nidx);
    unsigned long long pm = (((unsigned long long)bh << 32) | bl) >> l0;
    unsigned pml = (unsigned)pm, pmh = (unsigned)(pm >> 32);
    int pcp  = __popc(pml) + __popc(pmh);
    int wpcp = wpc32(pml) + wpc32(pmh) + (__popc(pmh) << 5);
    int Cge = CSn + pcp;
    int Sge = SSn + c * pcp + wpcp;                      // c = 64*gb + l0

    float sigma = (w >= 0.0f)
        ? (w * (float)Sge + b * (float)Cge)
        : (w * (float)(Stot - Sge) + b * (float)(Ctot - Cge));

    // Broadcast the 16 h-sums to all lanes.
    float s16[HID];
#pragma unroll
    for (int k = 0; k < HID; ++k) s16[k] = __shfl(sigma, k);

    // ---- Epilogue: emb[d] = (sum_k s16[k]*W2[k][d] + Ctot*b2[d]) / max(Ctot,1)
    const float cnt = (float)Ctot;
    const float inv = 1.0f / fmaxf(cnt, 1.0f);
    const float2* __restrict__ W2v = (const float2*)W2;   // [16][64] float2
    float2 bv = ((const float2*)b2)[lane];
    float e0 = cnt * bv.x;
    float e1 = cnt * bv.y;
#pragma unroll
    for (int k = 0; k < HID; ++k) {
        float2 wv = W2v[k * 64 + lane];
        e0 = fmaf(s16[k], wv.x, e0);
        e1 = fmaf(s16[k], wv.y, e1);
    }
    ((float2*)out)[row * 64 + lane] = make_float2(e0 * inv, e1 * inv);
}

extern "C" void kernel_launch(void* const* d_in, const int* in_sizes, int n_in,
                              void* d_out, int out_size, void* d_ws, size_t ws_size,
                              hipStream_t stream) {
    const float* M  = (const float*)d_in[0];   // [50000, 2000]
    const float* W1 = (const float*)d_in[1];   // [1, 16]
    const float* b1 = (const float*)d_in[2];   // [16]
    const float* W2 = (const float*)d_in[3];   // [16, 128]
    const float* b2 = (const float*)d_in[4];   // [128]
    float* out = (float*)d_out;                // [50000, 128]

    bitmap_mean_kernel<<<NUM_LEARNERS / 4, 256, 0, stream>>>(
        M, W1, b1, W2, b2, out);
}